// Round 14
// baseline (378.918 us; speedup 1.0000x reference)
//
#include <hip/hip_runtime.h>

typedef __attribute__((ext_vector_type(4))) float f32x4;
typedef __attribute__((ext_vector_type(2))) long long i64x2;

static constexpr int D = 256;
static constexpr float INV_T = 2.0f;                 // 1 / temperature(0.5)
static constexpr float KEXP2 = 2.8853900817779268f;  // 2*log2(e): exp(2x)=2^(KEXP2*x)
static constexpr int TTILE = 64;                     // 8192 / 128
static constexpr int NT = TTILE * (TTILE + 1) / 2;   // 2080 upper-triangle tiles
static constexpr int GRID = 512;                     // persistent blocks, 2/CU
static constexpr int NPLANE = 2 * TTILE;             // 128 partial planes
// zn fp8 paired-kk fragment layout (verified R10-R13, absmax=0): per 128-row
// tile contiguous 32 KB; byte = ti*32768 + rb*4096 + kkp*1024 + lane*16 +
// half*8 + e, rb=(row>>4)&7, kkp=k>>6, half=(k>>5)&1,
// lane=((k>>3)&3)*16+(row&15), e=k&7.

__device__ inline float fexp2(float x) {
#if __has_builtin(__builtin_amdgcn_exp2f)
    return __builtin_amdgcn_exp2f(x);
#else
    return exp2f(x);
#endif
}
__device__ inline unsigned int cvt4_fp8(float a, float b, float c, float d) {
    int v = __builtin_amdgcn_cvt_pk_fp8_f32(a, b, 0, false);
    v = __builtin_amdgcn_cvt_pk_fp8_f32(c, d, v, true);
    return (unsigned int)v;
}
__device__ inline unsigned int aload(unsigned int* p) {
    return __hip_atomic_load(p, __ATOMIC_ACQUIRE, __HIP_MEMORY_SCOPE_AGENT);
}

// Zero the barrier state every call (no cross-replay invariants; ws contents
// arbitrary on first call / after poison).
__global__ void k_init(unsigned int* done, unsigned int* rel) {
    int t = threadIdx.x;
    if (t < GRID) done[t] = 0u;
    if (t == 0) *rel = 0u;
}

// Flag-tree grid barrier: each block bumps its OWN slot (no contended RMW);
// block 0's 256 threads poll the 512 slots, then bump one release word all
// blocks spin on. Cross-XCD visibility via device-scope atomics +
// __threadfence (pattern validated cross-block in R12/R13).
__device__ inline void grid_barrier(unsigned int* done, unsigned int* rel,
                                    int p, int bid, int tid) {
    __threadfence();            // release this block's prior writes
    __syncthreads();
    if (tid == 0)
        __hip_atomic_fetch_add(&done[bid], 1u, __ATOMIC_RELEASE, __HIP_MEMORY_SCOPE_AGENT);
    if (bid == 0) {
        for (int s = tid; s < GRID; s += 256)
            while (aload(&done[s]) < (unsigned int)(p + 1))
                __builtin_amdgcn_s_sleep(1);
        __syncthreads();
        if (tid == 0)
            __hip_atomic_fetch_add(rel, 1u, __ATOMIC_RELEASE, __HIP_MEMORY_SCOPE_AGENT);
    }
    if (tid == 0)
        while (aload(rel) < (unsigned int)(p + 1))
            __builtin_amdgcn_s_sleep(1);
    __syncthreads();
    __threadfence();            // acquire other blocks' writes
}

__global__ __launch_bounds__(256, 2)
void k_fused(const float* __restrict__ zi, const float* __restrict__ zj,
             unsigned char* __restrict__ zn, float* __restrict__ diag,
             float* __restrict__ pos_partial, float* __restrict__ part,
             unsigned int* __restrict__ done, unsigned int* __restrict__ rel,
             float* __restrict__ P, float* __restrict__ out, int B, int N) {
    __shared__ float red[4];
    const int tid = threadIdx.x;
    const int bid = (int)blockIdx.x;
    const int lane = tid & 63, wv = tid >> 6;
    const int l15 = lane & 15, lhi = lane >> 4;

    // ---------------- Phase 0: normalize -> fp8 fragment layout ----------------
    float pdsum = 0.f;
#pragma unroll
    for (int it = 0; it < 2; ++it) {
        const int i = bid * 8 + wv * 2 + it;     // pair index, exactly covers B=4096
        if (i < B) {
            float4 vi = reinterpret_cast<const float4*>(zi + (size_t)i * D)[lane];
            float4 vj = reinterpret_cast<const float4*>(zj + (size_t)i * D)[lane];
            float ssi = vi.x * vi.x + vi.y * vi.y + vi.z * vi.z + vi.w * vi.w;
            float ssj = vj.x * vj.x + vj.y * vj.y + vj.z * vj.z + vj.w * vj.w;
#pragma unroll
            for (int off = 32; off >= 1; off >>= 1) {
                ssi += __shfl_xor(ssi, off, 64);
                ssj += __shfl_xor(ssj, off, 64);
            }
            float rni = rsqrtf(ssi), rnj = rsqrtf(ssj);
            unsigned int pa = cvt4_fp8(vi.x * rni, vi.y * rni, vi.z * rni, vi.w * rni);
            unsigned int pb = cvt4_fp8(vj.x * rnj, vj.y * rnj, vj.z * rnj, vj.w * rnj);
            float fa0 = __builtin_amdgcn_cvt_f32_fp8((int)pa, 0);
            float fa1 = __builtin_amdgcn_cvt_f32_fp8((int)pa, 1);
            float fa2 = __builtin_amdgcn_cvt_f32_fp8((int)pa, 2);
            float fa3 = __builtin_amdgcn_cvt_f32_fp8((int)pa, 3);
            float fb0 = __builtin_amdgcn_cvt_f32_fp8((int)pb, 0);
            float fb1 = __builtin_amdgcn_cvt_f32_fp8((int)pb, 1);
            float fb2 = __builtin_amdgcn_cvt_f32_fp8((int)pb, 2);
            float fb3 = __builtin_amdgcn_cvt_f32_fp8((int)pb, 3);
            float sdi = fa0 * fa0 + fa1 * fa1 + fa2 * fa2 + fa3 * fa3;
            float sdj = fb0 * fb0 + fb1 * fb1 + fb2 * fb2 + fb3 * fb3;
            float pd  = fa0 * fb0 + fa1 * fb1 + fa2 * fb2 + fa3 * fb3;
#pragma unroll
            for (int off = 32; off >= 1; off >>= 1) {
                sdi += __shfl_xor(sdi, off, 64);
                sdj += __shfl_xor(sdj, off, 64);
                pd  += __shfl_xor(pd, off, 64);
            }
            unsigned int qa = __shfl_xor(pa, 1, 64);
            unsigned int qb = __shfl_xor(pb, 1, 64);
            if ((lane & 1) == 0) {
                int m = lane >> 1;   // 0..31 -> k = 8m..8m+7
                size_t base = (size_t)(m >> 3) * 1024 + (size_t)((m & 3) * 16) * 16
                            + (size_t)(((m >> 2) & 1)) * 8;
                size_t offA = (size_t)(i >> 4) * 4096 + base + (size_t)(i & 15) * 16;
                int ib = i + B;
                size_t offB = (size_t)(ib >> 4) * 4096 + base + (size_t)(ib & 15) * 16;
                *reinterpret_cast<unsigned long long*>(zn + offA) =
                    ((unsigned long long)qa << 32) | pa;
                *reinterpret_cast<unsigned long long*>(zn + offB) =
                    ((unsigned long long)qb << 32) | pb;
            }
            if (lane == 0) {
                diag[i]     = -fexp2(KEXP2 * sdi);
                diag[i + B] = -fexp2(KEXP2 * sdj);
                pdsum += pd;
            }
        }
    }
    if (lane == 0) red[wv] = pdsum;
    __syncthreads();
    if (tid == 0)
        pos_partial[bid] = 2.0f * INV_T * (red[0] + red[1] + red[2] + red[3]);

    grid_barrier(done, rel, 0, bid, tid);

    // ---------------- Phase 1: sim tiles (grid-strided) ----------------
    const int wr = wv >> 1, wc = wv & 1;         // wave grid 2x2, 64x64 each
    for (int t = bid; t < NT; t += GRID) {
        // XCD swizzle + closed-form upper-triangle decode (verified R13)
        const int swz = (t & 7) * (NT / 8) + (t >> 3);
        int ti = (int)(((float)(2 * TTILE + 1) -
                        sqrtf((float)((2 * TTILE + 1) * (2 * TTILE + 1)) - 8.0f * (float)swz)) * 0.5f);
        ti = (ti < 0) ? 0 : ((ti > TTILE - 1) ? TTILE - 1 : ti);
        while (ti > 0 && (ti * TTILE - ((ti * (ti - 1)) >> 1)) > swz) --ti;
        while (((ti + 1) * TTILE - (((ti + 1) * ti) >> 1)) <= swz) ++ti;
        const int tj = ti + (swz - (ti * TTILE - ((ti * (ti - 1)) >> 1)));

        const i64x2* Ap = reinterpret_cast<const i64x2*>(zn + (size_t)ti * 32768);
        const i64x2* Bp = reinterpret_cast<const i64x2*>(zn + (size_t)tj * 32768);

        f32x4 acc[4][4];
#pragma unroll
        for (int r = 0; r < 4; ++r)
#pragma unroll
            for (int c = 0; c < 4; ++c) acc[r][c] = (f32x4){0.f, 0.f, 0.f, 0.f};

#pragma unroll
        for (int kkp = 0; kkp < 4; ++kkp) {
            i64x2 a_[4], b_[4];
#pragma unroll
            for (int r = 0; r < 4; ++r)
                a_[r] = Ap[((wr * 4 + r) * 4 + kkp) * 64 + lane];
#pragma unroll
            for (int c = 0; c < 4; ++c)
                b_[c] = Bp[((wc * 4 + c) * 4 + kkp) * 64 + lane];
#pragma unroll
            for (int r = 0; r < 4; ++r)
#pragma unroll
                for (int c = 0; c < 4; ++c)
                    acc[r][c] = __builtin_amdgcn_mfma_f32_16x16x32_fp8_fp8(
                        a_[r].x, b_[c].x, acc[r][c], 0, 0, 0);
#pragma unroll
            for (int r = 0; r < 4; ++r)
#pragma unroll
                for (int c = 0; c < 4; ++c)
                    acc[r][c] = __builtin_amdgcn_mfma_f32_16x16x32_fp8_fp8(
                        a_[r].y, b_[c].y, acc[r][c], 0, 0, 0);
        }

        // tail: e=exp(2*sim); row-sums -> plane 2*tj+wc, col-sums -> plane 2*ti+wr
        float cs[4] = {0.f, 0.f, 0.f, 0.f};
#pragma unroll
        for (int r = 0; r < 4; ++r) {
            float rq0 = 0.f, rq1 = 0.f, rq2 = 0.f, rq3 = 0.f;
#pragma unroll
            for (int c = 0; c < 4; ++c) {
                float e0 = fexp2(KEXP2 * acc[r][c][0]);
                float e1 = fexp2(KEXP2 * acc[r][c][1]);
                float e2 = fexp2(KEXP2 * acc[r][c][2]);
                float e3 = fexp2(KEXP2 * acc[r][c][3]);
                rq0 += e0; rq1 += e1; rq2 += e2; rq3 += e3;
                cs[c] += e0 + e1 + e2 + e3;
            }
#pragma unroll
            for (int off = 1; off <= 8; off <<= 1) {
                rq0 += __shfl_xor(rq0, off, 64);
                rq1 += __shfl_xor(rq1, off, 64);
                rq2 += __shfl_xor(rq2, off, 64);
                rq3 += __shfl_xor(rq3, off, 64);
            }
            if (l15 == 0) {
                f32x4 o = (f32x4){rq0, rq1, rq2, rq3};
                *reinterpret_cast<f32x4*>(
                    P + (size_t)(2 * tj + wc) * N + ti * 128 + wr * 64 + r * 16 + lhi * 4) = o;
            }
        }
        if (ti != tj) {
#pragma unroll
            for (int c = 0; c < 4; ++c) {
                float v = cs[c];
                v += __shfl_xor(v, 16, 64);
                v += __shfl_xor(v, 32, 64);
                if (lhi == 0)
                    P[(size_t)(2 * ti + wr) * N + tj * 128 + wc * 64 + c * 16 + l15] = v;
            }
        }
    }

    grid_barrier(done, rel, 1, bid, tid);

    // ---------------- Phase 2: per-row LSE (16 rows/block) ----------------
    {
        const int row = bid * 16 + (tid >> 4);
        const int sub = tid & 15;
        float s = (sub == 0) ? diag[row] : 0.f;
#pragma unroll
        for (int d = 0; d < 8; ++d)
            s += P[(size_t)(sub * 8 + d) * N + row];
        s += __shfl_xor(s, 1, 64);
        s += __shfl_xor(s, 2, 64);
        s += __shfl_xor(s, 4, 64);
        s += __shfl_xor(s, 8, 64);
        float lg = (sub == 0) ? __logf(s) : 0.f;
        lg += __shfl_xor(lg, 16, 64);
        lg += __shfl_xor(lg, 32, 64);   // lane 0: sum of the wave's 4 row-logs
        if (lane == 0) red[wv] = lg;
        __syncthreads();
        if (tid == 0) part[bid] = red[0] + red[1] + red[2] + red[3];
    }

    grid_barrier(done, rel, 2, bid, tid);

    // ---------------- Phase 3: block 0 combines ----------------
    if (bid == 0) {
        float tt = 0.f;
        for (int i = tid; i < GRID; i += 256) tt += part[i] - pos_partial[i];
#pragma unroll
        for (int off = 32; off >= 1; off >>= 1) tt += __shfl_xor(tt, off, 64);
        if (lane == 0) red[wv] = tt;
        __syncthreads();
        if (tid == 0)
            out[0] = (red[0] + red[1] + red[2] + red[3]) / (float)N;
    }
}

extern "C" void kernel_launch(void* const* d_in, const int* in_sizes, int n_in,
                              void* d_out, int out_size, void* d_ws, size_t ws_size,
                              hipStream_t stream) {
    const float* zi = (const float*)d_in[0];
    const float* zj = (const float*)d_in[1];
    const int B = in_sizes[0] / D;   // 4096
    const int N = 2 * B;             // 8192

    char* ws = (char*)d_ws;
    unsigned char* zn = (unsigned char*)ws;              // N*D fp8 = 2 MB
    float* diag = (float*)(ws + (size_t)N * D);          // N f32
    float* pos_partial = diag + N;                       // GRID f32
    float* part = pos_partial + GRID;                    // GRID f32
    unsigned int* done = (unsigned int*)(part + GRID);   // GRID u32
    unsigned int* rel = done + GRID;                     // 1 u32 (+pad)
    float* P = (float*)(rel + 32);                       // 128*N f32 = 4 MB

    float* out = (float*)d_out;

    hipLaunchKernelGGL(k_init, dim3(1), dim3(GRID), 0, stream, done, rel);
    hipLaunchKernelGGL(k_fused, dim3(GRID), dim3(256), 0, stream,
                       zi, zj, zn, diag, pos_partial, part, done, rel, P, out, B, N);
}

// Round 15
// 48.737 us; speedup vs baseline: 7.7747x; 7.7747x over previous
//
#include <hip/hip_runtime.h>

typedef __attribute__((ext_vector_type(4))) float f32x4;
typedef __attribute__((ext_vector_type(2))) long long i64x2;

static constexpr int D = 256;
static constexpr float INV_T = 2.0f;                 // 1 / temperature(0.5)
static constexpr float KEXP2 = 2.8853900817779268f;  // 2*log2(e): exp(2x)=2^(KEXP2*x)
static constexpr int TTILE = 64;                     // 8192 / 128
static constexpr int NT = TTILE * (TTILE + 1) / 2;   // 2080 upper-triangle tiles
static constexpr int NPLANE = 2 * TTILE;             // 128 partial planes
static constexpr int LSE_BLOCKS = 256;
// zn fp8 paired-kk fragment layout (verified R10-R13, absmax=0): per 128-row
// tile contiguous 32 KB; byte = ti*32768 + rb*4096 + kkp*1024 + lane*16 +
// half*8 + e, rb=(row>>4)&7, kkp=k>>6, half=(k>>5)&1,
// lane=((k>>3)&3)*16+(row&15), e=k&7.

__device__ inline float fexp2(float x) {
#if __has_builtin(__builtin_amdgcn_exp2f)
    return __builtin_amdgcn_exp2f(x);
#else
    return exp2f(x);
#endif
}
__device__ inline unsigned int cvt4_fp8(float a, float b, float c, float d) {
    int v = __builtin_amdgcn_cvt_pk_fp8_f32(a, b, 0, false);
    v = __builtin_amdgcn_cvt_pk_fp8_f32(c, d, v, true);
    return (unsigned int)v;
}

// Kernel 1 (verified): normalize pair rows to fp8 in the fragment layout;
// diag[i] = -exp(2*selfdot_fp8); pos dot -> block partial; resets counter.
__global__ void k_norm(const float* __restrict__ zi, const float* __restrict__ zj,
                       unsigned char* __restrict__ zn, float* __restrict__ diag,
                       float* __restrict__ pos_partial, unsigned int* __restrict__ counter,
                       int B) {
    __shared__ float red[4];
    const int lane = threadIdx.x & 63;
    const int wv = threadIdx.x >> 6;
    const int i = blockIdx.x * 4 + wv;       // pair index
    if (blockIdx.x == 0 && threadIdx.x == 0) *counter = 0;
    if (i < B) {
        float4 vi = reinterpret_cast<const float4*>(zi + (size_t)i * D)[lane];
        float4 vj = reinterpret_cast<const float4*>(zj + (size_t)i * D)[lane];
        float ssi = vi.x * vi.x + vi.y * vi.y + vi.z * vi.z + vi.w * vi.w;
        float ssj = vj.x * vj.x + vj.y * vj.y + vj.z * vj.z + vj.w * vj.w;
#pragma unroll
        for (int off = 32; off >= 1; off >>= 1) {
            ssi += __shfl_xor(ssi, off, 64);
            ssj += __shfl_xor(ssj, off, 64);
        }
        float rni = rsqrtf(ssi), rnj = rsqrtf(ssj);
        unsigned int pa = cvt4_fp8(vi.x * rni, vi.y * rni, vi.z * rni, vi.w * rni);
        unsigned int pb = cvt4_fp8(vj.x * rnj, vj.y * rnj, vj.z * rnj, vj.w * rnj);
        float fa0 = __builtin_amdgcn_cvt_f32_fp8((int)pa, 0);
        float fa1 = __builtin_amdgcn_cvt_f32_fp8((int)pa, 1);
        float fa2 = __builtin_amdgcn_cvt_f32_fp8((int)pa, 2);
        float fa3 = __builtin_amdgcn_cvt_f32_fp8((int)pa, 3);
        float fb0 = __builtin_amdgcn_cvt_f32_fp8((int)pb, 0);
        float fb1 = __builtin_amdgcn_cvt_f32_fp8((int)pb, 1);
        float fb2 = __builtin_amdgcn_cvt_f32_fp8((int)pb, 2);
        float fb3 = __builtin_amdgcn_cvt_f32_fp8((int)pb, 3);
        float sdi = fa0 * fa0 + fa1 * fa1 + fa2 * fa2 + fa3 * fa3;
        float sdj = fb0 * fb0 + fb1 * fb1 + fb2 * fb2 + fb3 * fb3;
        float pd  = fa0 * fb0 + fa1 * fb1 + fa2 * fb2 + fa3 * fb3;
#pragma unroll
        for (int off = 32; off >= 1; off >>= 1) {
            sdi += __shfl_xor(sdi, off, 64);
            sdj += __shfl_xor(sdj, off, 64);
            pd  += __shfl_xor(pd, off, 64);
        }
        unsigned int qa = __shfl_xor(pa, 1, 64);
        unsigned int qb = __shfl_xor(pb, 1, 64);
        if ((lane & 1) == 0) {
            int m = lane >> 1;   // 0..31 -> k = 8m..8m+7
            size_t base = (size_t)(m >> 3) * 1024 + (size_t)((m & 3) * 16) * 16
                        + (size_t)(((m >> 2) & 1)) * 8;
            size_t offA = (size_t)(i >> 4) * 4096 + base + (size_t)(i & 15) * 16;
            int ib = i + B;
            size_t offB = (size_t)(ib >> 4) * 4096 + base + (size_t)(ib & 15) * 16;
            *reinterpret_cast<unsigned long long*>(zn + offA) =
                ((unsigned long long)qa << 32) | pa;
            *reinterpret_cast<unsigned long long*>(zn + offB) =
                ((unsigned long long)qb << 32) | pb;
        }
        if (lane == 0) {
            diag[i]     = -fexp2(KEXP2 * sdi);
            diag[i + B] = -fexp2(KEXP2 * sdj);
            red[wv] = pd;
        }
    } else if (lane == 0) {
        red[wv] = 0.f;
    }
    __syncthreads();
    if (threadIdx.x == 0)
        pos_partial[blockIdx.x] = 2.0f * INV_T * (red[0] + red[1] + red[2] + red[3]);
}

// Kernel 2: barrier-free, LDS-free upper-triangle 128x128 tiles; 2 waves per
// block, each wave owns 128 rows x 64 cols (acc = 128 VGPR). Intensity
// 87 FLOP/B vs 64 at the old 64x64 wave tile -> L2 traffic 266->200 MB
// (R11-R13's 3-way neutrality pinned k_main at the 64 FLOP/B CU balance
// point: co-bound on L2 + MFMA). 4 blocks/CU. Col-sum planes are written in
// 64-col halves -> P memset to 0 beforehand makes the holes exact.
__global__ __launch_bounds__(128, 2)
void k_main(const unsigned char* __restrict__ zn, float* __restrict__ P, int N) {
    const int tid = threadIdx.x;
    const int lane = tid & 63;
    const int wc = tid >> 6;                 // wave = column half (0/1)
    const int l15 = lane & 15, lhi = lane >> 4;

    // XCD-aware bijective swizzle (NT = 2080 = 8 * 260)
    const int bid = (int)blockIdx.x;
    const int swz = (bid & 7) * (NT / 8) + (bid >> 3);
    // closed-form upper-triangle decode (verified R13)
    int ti = (int)(((float)(2 * TTILE + 1) -
                    sqrtf((float)((2 * TTILE + 1) * (2 * TTILE + 1)) - 8.0f * (float)swz)) * 0.5f);
    ti = (ti < 0) ? 0 : ((ti > TTILE - 1) ? TTILE - 1 : ti);
    while (ti > 0 && (ti * TTILE - ((ti * (ti - 1)) >> 1)) > swz) --ti;
    while (((ti + 1) * TTILE - (((ti + 1) * ti) >> 1)) <= swz) ++ti;
    const int tj = ti + (swz - (ti * TTILE - ((ti * (ti - 1)) >> 1)));

    const i64x2* Ap = reinterpret_cast<const i64x2*>(zn + (size_t)ti * 32768);
    const i64x2* Bp = reinterpret_cast<const i64x2*>(zn + (size_t)tj * 32768);

    f32x4 acc[8][4];
#pragma unroll
    for (int r = 0; r < 8; ++r)
#pragma unroll
        for (int c = 0; c < 4; ++c) acc[r][c] = (f32x4){0.f, 0.f, 0.f, 0.f};

#pragma unroll
    for (int kkp = 0; kkp < 4; ++kkp) {
        i64x2 a_[8], b_[4];
#pragma unroll
        for (int r = 0; r < 8; ++r)
            a_[r] = Ap[(r * 4 + kkp) * 64 + lane];
#pragma unroll
        for (int c = 0; c < 4; ++c)
            b_[c] = Bp[((wc * 4 + c) * 4 + kkp) * 64 + lane];
        __builtin_amdgcn_s_setprio(1);
#pragma unroll
        for (int r = 0; r < 8; ++r)
#pragma unroll
            for (int c = 0; c < 4; ++c)
                acc[r][c] = __builtin_amdgcn_mfma_f32_16x16x32_fp8_fp8(
                    a_[r].x, b_[c].x, acc[r][c], 0, 0, 0);
#pragma unroll
        for (int r = 0; r < 8; ++r)
#pragma unroll
            for (int c = 0; c < 4; ++c)
                acc[r][c] = __builtin_amdgcn_mfma_f32_16x16x32_fp8_fp8(
                    a_[r].y, b_[c].y, acc[r][c], 0, 0, 0);
        __builtin_amdgcn_s_setprio(0);
    }

    // tail: e=exp(2*sim). Row-sums -> plane 2*tj+wc (full 128-row stripe per
    // wave); col-sums -> plane 2*ti+wc, cols [tj*128+wc*64, +64) (half
    // stripe; other half is the memset zero). row = r*16+lhi*4+q (tile-local),
    // col = wc*64 + c*16 + l15.
    float cs[4] = {0.f, 0.f, 0.f, 0.f};
#pragma unroll
    for (int r = 0; r < 8; ++r) {
        float rq0 = 0.f, rq1 = 0.f, rq2 = 0.f, rq3 = 0.f;
#pragma unroll
        for (int c = 0; c < 4; ++c) {
            float e0 = fexp2(KEXP2 * acc[r][c][0]);
            float e1 = fexp2(KEXP2 * acc[r][c][1]);
            float e2 = fexp2(KEXP2 * acc[r][c][2]);
            float e3 = fexp2(KEXP2 * acc[r][c][3]);
            rq0 += e0; rq1 += e1; rq2 += e2; rq3 += e3;
            cs[c] += e0 + e1 + e2 + e3;
        }
#pragma unroll
        for (int off = 1; off <= 8; off <<= 1) {
            rq0 += __shfl_xor(rq0, off, 64);
            rq1 += __shfl_xor(rq1, off, 64);
            rq2 += __shfl_xor(rq2, off, 64);
            rq3 += __shfl_xor(rq3, off, 64);
        }
        if (l15 == 0) {
            f32x4 o = (f32x4){rq0, rq1, rq2, rq3};
            *reinterpret_cast<f32x4*>(
                P + (size_t)(2 * tj + wc) * N + ti * 128 + r * 16 + lhi * 4) = o;
        }
    }
    if (ti != tj) {
#pragma unroll
        for (int c = 0; c < 4; ++c) {
            float v = cs[c];
            v += __shfl_xor(v, 16, 64);
            v += __shfl_xor(v, 32, 64);
            if (lhi == 0)
                P[(size_t)(2 * ti + wc) * N + tj * 128 + wc * 64 + c * 16 + l15] = v;
        }
    }
}

// Kernel 3: per-row plane sum (8 threads/row x 16 planes -> 8x the latency
// parallelism of the old 1-thread/row 128-deep chain) + diag, log; block
// partial; last block combines with pos partials -> loss.
__global__ void k_lse(const float* __restrict__ P, const float* __restrict__ diag,
                      const float* __restrict__ pos_partial, int n_pos,
                      float* __restrict__ part, unsigned int* __restrict__ counter,
                      float* __restrict__ out, int N) {
    __shared__ float red[4];
    const int tid = threadIdx.x;
    const int lane = tid & 63, wv = tid >> 6;
    const int row = blockIdx.x * 32 + (tid >> 3);
    const int sub = tid & 7;
    float s = 0.f;
#pragma unroll
    for (int d = 0; d < 16; ++d)
        s += P[(size_t)(sub * 16 + d) * N + row];
    s += __shfl_xor(s, 1, 64);
    s += __shfl_xor(s, 2, 64);
    s += __shfl_xor(s, 4, 64);
    float lg = (sub == 0) ? __logf(s + diag[row]) : 0.f;
    lg += __shfl_xor(lg, 8, 64);
    lg += __shfl_xor(lg, 16, 64);
    lg += __shfl_xor(lg, 32, 64);
    if (lane == 0) red[wv] = lg;
    __syncthreads();
    bool last = false;
    if (tid == 0) {
        part[blockIdx.x] = red[0] + red[1] + red[2] + red[3];
        __threadfence();
        last = (atomicAdd(counter, 1u) == LSE_BLOCKS - 1);
    }
    __shared__ int lastflag;
    if (tid == 0) lastflag = last ? 1 : 0;
    __syncthreads();
    if (lastflag) {
        __threadfence();
        float t = 0.f;
        for (int i = tid; i < LSE_BLOCKS; i += 256) t += part[i];
        for (int i = tid; i < n_pos; i += 256) t -= pos_partial[i];
#pragma unroll
        for (int off = 32; off >= 1; off >>= 1) t += __shfl_xor(t, off, 64);
        if (lane == 0) red[wv] = t;
        __syncthreads();
        if (tid == 0)
            out[0] = (red[0] + red[1] + red[2] + red[3]) / (float)N;
    }
}

extern "C" void kernel_launch(void* const* d_in, const int* in_sizes, int n_in,
                              void* d_out, int out_size, void* d_ws, size_t ws_size,
                              hipStream_t stream) {
    const float* zi = (const float*)d_in[0];
    const float* zj = (const float*)d_in[1];
    const int B = in_sizes[0] / D;   // 4096
    const int N = 2 * B;             // 8192

    char* ws = (char*)d_ws;
    unsigned char* zn = (unsigned char*)ws;              // N*D fp8 = 2 MB
    float* diag = (float*)(ws + (size_t)N * D);          // N f32
    float* pos_partial = diag + N;                       // 1024 f32
    float* part = pos_partial + 1024;                    // 256 f32
    unsigned int* counter = (unsigned int*)(part + 256); // 1 u32
    float* P = (float*)(counter + 32);                   // 128*N f32 = 4 MB

    float* out = (float*)d_out;

    const int npb = B / 4;  // 1024 k_norm blocks == pos partials
    hipMemsetAsync(P, 0, (size_t)NPLANE * N * sizeof(float), stream);
    hipLaunchKernelGGL(k_norm, dim3(npb), dim3(256), 0, stream, zi, zj, zn, diag,
                       pos_partial, counter, B);
    hipLaunchKernelGGL(k_main, dim3(NT), dim3(128), 0, stream, zn, P, N);
    hipLaunchKernelGGL(k_lse, dim3(LSE_BLOCKS), dim3(256), 0, stream, P, diag,
                       pos_partial, npb, part, counter, out, N);
}

// Round 16
// 44.461 us; speedup vs baseline: 8.5225x; 1.0962x over previous
//
#include <hip/hip_runtime.h>

typedef __attribute__((ext_vector_type(4))) float f32x4;
typedef __attribute__((ext_vector_type(2))) long long i64x2;

static constexpr int D = 256;
static constexpr float INV_T = 2.0f;                 // 1 / temperature(0.5)
static constexpr float KEXP2 = 2.8853900817779268f;  // 2*log2(e): exp(2x)=2^(KEXP2*x)
static constexpr int TTILE = 64;                     // 8192 / 128
static constexpr int NT = TTILE * (TTILE + 1) / 2;   // 2080 upper-triangle tiles
static constexpr int NPLANE = 2 * TTILE;             // 128 partial planes
static constexpr int LSE_BLOCKS = 256;
// zn fp8 paired-kk fragment layout (verified R10-R15, absmax=0): per 128-row
// tile contiguous 32 KB; byte = ti*32768 + rb*4096 + kkp*1024 + lane*16 +
// half*8 + e, rb=(row>>4)&7, kkp=k>>6, half=(k>>5)&1,
// lane=((k>>3)&3)*16+(row&15), e=k&7.

__device__ inline float fexp2(float x) {
#if __has_builtin(__builtin_amdgcn_exp2f)
    return __builtin_amdgcn_exp2f(x);
#else
    return exp2f(x);
#endif
}
__device__ inline unsigned int cvt4_fp8(float a, float b, float c, float d) {
    int v = __builtin_amdgcn_cvt_pk_fp8_f32(a, b, 0, false);
    v = __builtin_amdgcn_cvt_pk_fp8_f32(c, d, v, true);
    return (unsigned int)v;
}

// Kernel 1 (verified): normalize pair rows to fp8 in the fragment layout;
// diag[i] = -exp(2*selfdot_fp8); pos dot -> block partial; resets counter.
__global__ void k_norm(const float* __restrict__ zi, const float* __restrict__ zj,
                       unsigned char* __restrict__ zn, float* __restrict__ diag,
                       float* __restrict__ pos_partial, unsigned int* __restrict__ counter,
                       int B) {
    __shared__ float red[4];
    const int lane = threadIdx.x & 63;
    const int wv = threadIdx.x >> 6;
    const int i = blockIdx.x * 4 + wv;       // pair index
    if (blockIdx.x == 0 && threadIdx.x == 0) *counter = 0;
    if (i < B) {
        float4 vi = reinterpret_cast<const float4*>(zi + (size_t)i * D)[lane];
        float4 vj = reinterpret_cast<const float4*>(zj + (size_t)i * D)[lane];
        float ssi = vi.x * vi.x + vi.y * vi.y + vi.z * vi.z + vi.w * vi.w;
        float ssj = vj.x * vj.x + vj.y * vj.y + vj.z * vj.z + vj.w * vj.w;
#pragma unroll
        for (int off = 32; off >= 1; off >>= 1) {
            ssi += __shfl_xor(ssi, off, 64);
            ssj += __shfl_xor(ssj, off, 64);
        }
        float rni = rsqrtf(ssi), rnj = rsqrtf(ssj);
        unsigned int pa = cvt4_fp8(vi.x * rni, vi.y * rni, vi.z * rni, vi.w * rni);
        unsigned int pb = cvt4_fp8(vj.x * rnj, vj.y * rnj, vj.z * rnj, vj.w * rnj);
        float fa0 = __builtin_amdgcn_cvt_f32_fp8((int)pa, 0);
        float fa1 = __builtin_amdgcn_cvt_f32_fp8((int)pa, 1);
        float fa2 = __builtin_amdgcn_cvt_f32_fp8((int)pa, 2);
        float fa3 = __builtin_amdgcn_cvt_f32_fp8((int)pa, 3);
        float fb0 = __builtin_amdgcn_cvt_f32_fp8((int)pb, 0);
        float fb1 = __builtin_amdgcn_cvt_f32_fp8((int)pb, 1);
        float fb2 = __builtin_amdgcn_cvt_f32_fp8((int)pb, 2);
        float fb3 = __builtin_amdgcn_cvt_f32_fp8((int)pb, 3);
        float sdi = fa0 * fa0 + fa1 * fa1 + fa2 * fa2 + fa3 * fa3;
        float sdj = fb0 * fb0 + fb1 * fb1 + fb2 * fb2 + fb3 * fb3;
        float pd  = fa0 * fb0 + fa1 * fb1 + fa2 * fb2 + fa3 * fb3;
#pragma unroll
        for (int off = 32; off >= 1; off >>= 1) {
            sdi += __shfl_xor(sdi, off, 64);
            sdj += __shfl_xor(sdj, off, 64);
            pd  += __shfl_xor(pd, off, 64);
        }
        unsigned int qa = __shfl_xor(pa, 1, 64);
        unsigned int qb = __shfl_xor(pb, 1, 64);
        if ((lane & 1) == 0) {
            int m = lane >> 1;   // 0..31 -> k = 8m..8m+7
            size_t base = (size_t)(m >> 3) * 1024 + (size_t)((m & 3) * 16) * 16
                        + (size_t)(((m >> 2) & 1)) * 8;
            size_t offA = (size_t)(i >> 4) * 4096 + base + (size_t)(i & 15) * 16;
            int ib = i + B;
            size_t offB = (size_t)(ib >> 4) * 4096 + base + (size_t)(ib & 15) * 16;
            *reinterpret_cast<unsigned long long*>(zn + offA) =
                ((unsigned long long)qa << 32) | pa;
            *reinterpret_cast<unsigned long long*>(zn + offB) =
                ((unsigned long long)qb << 32) | pb;
        }
        if (lane == 0) {
            diag[i]     = -fexp2(KEXP2 * sdi);
            diag[i + B] = -fexp2(KEXP2 * sdj);
            red[wv] = pd;
        }
    } else if (lane == 0) {
        red[wv] = 0.f;
    }
    __syncthreads();
    if (threadIdx.x == 0)
        pos_partial[blockIdx.x] = 2.0f * INV_T * (red[0] + red[1] + red[2] + red[3]);
}

// Kernel 2 (R15 structure, now self-covering): barrier-free, LDS-free
// upper-triangle 128x128 tiles; 2 waves/block, each wave owns 128 rows x 64
// cols (intensity 87 FLOP/B). Col-sum stripes are written in 64-col halves;
// each wave ZERO-FILLS the complementary half of its own plane (one 256B
// coalesced store) -- replaces R15's hipMemsetAsync(P), which profiled at
// 40.3us/dispatch (104 GB/s rocclr fill) and dominated the whole pipeline.
__global__ __launch_bounds__(128, 2)
void k_main(const unsigned char* __restrict__ zn, float* __restrict__ P, int N) {
    const int tid = threadIdx.x;
    const int lane = tid & 63;
    const int wc = tid >> 6;                 // wave = column half (0/1)
    const int l15 = lane & 15, lhi = lane >> 4;

    // XCD-aware bijective swizzle (NT = 2080 = 8 * 260)
    const int bid = (int)blockIdx.x;
    const int swz = (bid & 7) * (NT / 8) + (bid >> 3);
    // closed-form upper-triangle decode (verified R13)
    int ti = (int)(((float)(2 * TTILE + 1) -
                    sqrtf((float)((2 * TTILE + 1) * (2 * TTILE + 1)) - 8.0f * (float)swz)) * 0.5f);
    ti = (ti < 0) ? 0 : ((ti > TTILE - 1) ? TTILE - 1 : ti);
    while (ti > 0 && (ti * TTILE - ((ti * (ti - 1)) >> 1)) > swz) --ti;
    while (((ti + 1) * TTILE - (((ti + 1) * ti) >> 1)) <= swz) ++ti;
    const int tj = ti + (swz - (ti * TTILE - ((ti * (ti - 1)) >> 1)));

    const i64x2* Ap = reinterpret_cast<const i64x2*>(zn + (size_t)ti * 32768);
    const i64x2* Bp = reinterpret_cast<const i64x2*>(zn + (size_t)tj * 32768);

    f32x4 acc[8][4];
#pragma unroll
    for (int r = 0; r < 8; ++r)
#pragma unroll
        for (int c = 0; c < 4; ++c) acc[r][c] = (f32x4){0.f, 0.f, 0.f, 0.f};

#pragma unroll
    for (int kkp = 0; kkp < 4; ++kkp) {
        i64x2 a_[8], b_[4];
#pragma unroll
        for (int r = 0; r < 8; ++r)
            a_[r] = Ap[(r * 4 + kkp) * 64 + lane];
#pragma unroll
        for (int c = 0; c < 4; ++c)
            b_[c] = Bp[((wc * 4 + c) * 4 + kkp) * 64 + lane];
        __builtin_amdgcn_s_setprio(1);
#pragma unroll
        for (int r = 0; r < 8; ++r)
#pragma unroll
            for (int c = 0; c < 4; ++c)
                acc[r][c] = __builtin_amdgcn_mfma_f32_16x16x32_fp8_fp8(
                    a_[r].x, b_[c].x, acc[r][c], 0, 0, 0);
#pragma unroll
        for (int r = 0; r < 8; ++r)
#pragma unroll
            for (int c = 0; c < 4; ++c)
                acc[r][c] = __builtin_amdgcn_mfma_f32_16x16x32_fp8_fp8(
                    a_[r].y, b_[c].y, acc[r][c], 0, 0, 0);
        __builtin_amdgcn_s_setprio(0);
    }

    // tail: e=exp(2*sim). Row-sums -> plane 2*tj+wc (full 128-row stripe per
    // wave); col-sums -> plane 2*ti+wc cols [tj*128+wc*64,+64), zeros to the
    // complementary half. row = r*16+lhi*4+q (tile-local), col = wc*64+c*16+l15.
    float cs[4] = {0.f, 0.f, 0.f, 0.f};
#pragma unroll
    for (int r = 0; r < 8; ++r) {
        float rq0 = 0.f, rq1 = 0.f, rq2 = 0.f, rq3 = 0.f;
#pragma unroll
        for (int c = 0; c < 4; ++c) {
            float e0 = fexp2(KEXP2 * acc[r][c][0]);
            float e1 = fexp2(KEXP2 * acc[r][c][1]);
            float e2 = fexp2(KEXP2 * acc[r][c][2]);
            float e3 = fexp2(KEXP2 * acc[r][c][3]);
            rq0 += e0; rq1 += e1; rq2 += e2; rq3 += e3;
            cs[c] += e0 + e1 + e2 + e3;
        }
#pragma unroll
        for (int off = 1; off <= 8; off <<= 1) {
            rq0 += __shfl_xor(rq0, off, 64);
            rq1 += __shfl_xor(rq1, off, 64);
            rq2 += __shfl_xor(rq2, off, 64);
            rq3 += __shfl_xor(rq3, off, 64);
        }
        if (l15 == 0) {
            f32x4 o = (f32x4){rq0, rq1, rq2, rq3};
            *reinterpret_cast<f32x4*>(
                P + (size_t)(2 * tj + wc) * N + ti * 128 + r * 16 + lhi * 4) = o;
        }
    }
    if (ti != tj) {
#pragma unroll
        for (int c = 0; c < 4; ++c) {
            float v = cs[c];
            v += __shfl_xor(v, 16, 64);
            v += __shfl_xor(v, 32, 64);
            if (lhi == 0)
                P[(size_t)(2 * ti + wc) * N + tj * 128 + wc * 64 + c * 16 + l15] = v;
        }
        // zero-fill the complementary 64-col half of this wave's plane
        // (exactly-once: only this wave owns these slots)
        P[(size_t)(2 * ti + wc) * N + tj * 128 + (1 - wc) * 64 + lane] = 0.f;
    }
}

// Kernel 3 (verified R15): per-row plane sum (8 threads/row x 16 planes) +
// diag, log; block partial; last block combines with pos partials -> loss.
__global__ void k_lse(const float* __restrict__ P, const float* __restrict__ diag,
                      const float* __restrict__ pos_partial, int n_pos,
                      float* __restrict__ part, unsigned int* __restrict__ counter,
                      float* __restrict__ out, int N) {
    __shared__ float red[4];
    const int tid = threadIdx.x;
    const int lane = tid & 63, wv = tid >> 6;
    const int row = blockIdx.x * 32 + (tid >> 3);
    const int sub = tid & 7;
    float s = 0.f;
#pragma unroll
    for (int d = 0; d < 16; ++d)
        s += P[(size_t)(sub * 16 + d) * N + row];
    s += __shfl_xor(s, 1, 64);
    s += __shfl_xor(s, 2, 64);
    s += __shfl_xor(s, 4, 64);
    float lg = (sub == 0) ? __logf(s + diag[row]) : 0.f;
    lg += __shfl_xor(lg, 8, 64);
    lg += __shfl_xor(lg, 16, 64);
    lg += __shfl_xor(lg, 32, 64);
    if (lane == 0) red[wv] = lg;
    __syncthreads();
    bool last = false;
    if (tid == 0) {
        part[blockIdx.x] = red[0] + red[1] + red[2] + red[3];
        __threadfence();
        last = (atomicAdd(counter, 1u) == LSE_BLOCKS - 1);
    }
    __shared__ int lastflag;
    if (tid == 0) lastflag = last ? 1 : 0;
    __syncthreads();
    if (lastflag) {
        __threadfence();
        float t = 0.f;
        for (int i = tid; i < LSE_BLOCKS; i += 256) t += part[i];
        for (int i = tid; i < n_pos; i += 256) t -= pos_partial[i];
#pragma unroll
        for (int off = 32; off >= 1; off >>= 1) t += __shfl_xor(t, off, 64);
        if (lane == 0) red[wv] = t;
        __syncthreads();
        if (tid == 0)
            out[0] = (red[0] + red[1] + red[2] + red[3]) / (float)N;
    }
}

extern "C" void kernel_launch(void* const* d_in, const int* in_sizes, int n_in,
                              void* d_out, int out_size, void* d_ws, size_t ws_size,
                              hipStream_t stream) {
    const float* zi = (const float*)d_in[0];
    const float* zj = (const float*)d_in[1];
    const int B = in_sizes[0] / D;   // 4096
    const int N = 2 * B;             // 8192

    char* ws = (char*)d_ws;
    unsigned char* zn = (unsigned char*)ws;              // N*D fp8 = 2 MB
    float* diag = (float*)(ws + (size_t)N * D);          // N f32
    float* pos_partial = diag + N;                       // 1024 f32
    float* part = pos_partial + 1024;                    // 256 f32
    unsigned int* counter = (unsigned int*)(part + 256); // 1 u32
    float* P = (float*)(counter + 32);                   // 128*N f32 = 4 MB

    float* out = (float*)d_out;

    const int npb = B / 4;  // 1024 k_norm blocks == pos partials
    hipLaunchKernelGGL(k_norm, dim3(npb), dim3(256), 0, stream, zi, zj, zn, diag,
                       pos_partial, counter, B);
    hipLaunchKernelGGL(k_main, dim3(NT), dim3(128), 0, stream, zn, P, N);
    hipLaunchKernelGGL(k_lse, dim3(LSE_BLOCKS), dim3(256), 0, stream, P, diag,
                       pos_partial, npb, part, counter, out, N);
}